// Round 5
// baseline (324.306 us; speedup 1.0000x reference)
//
#include <hip/hip_runtime.h>
#include <stdint.h>
#include <math.h>

typedef unsigned short u16;
typedef float f32x4 __attribute__((ext_vector_type(4)));
typedef __bf16 bf16x8 __attribute__((ext_vector_type(8)));

__device__ __forceinline__ u16 f2bf(float f) {
    union { float f; uint32_t u; } c; c.f = f;
    return (u16)((c.u + 0x7FFFu + ((c.u >> 16) & 1u)) >> 16);
}

__device__ __forceinline__ void gload_lds16(const void* g, void* l) {
    __builtin_amdgcn_global_load_lds(
        (const __attribute__((address_space(1))) unsigned int*)g,
        (__attribute__((address_space(3))) unsigned int*)l, 16, 0, 0);
}

// ---------------- LayerNorm: z [4096,1024] fp32 -> zn bf16 ----------------
__global__ __launch_bounds__(256) void ln_kernel(const float* __restrict__ z,
                                                 const float* __restrict__ sc,
                                                 const float* __restrict__ bs,
                                                 u16* __restrict__ zn) {
    const int row = blockIdx.x, tid = threadIdx.x;
    const float4 v = ((const float4*)(z + row * 1024))[tid];
    float s = v.x + v.y + v.z + v.w;
    #pragma unroll
    for (int off = 32; off > 0; off >>= 1) s += __shfl_xor(s, off);
    __shared__ float red[8];
    if ((tid & 63) == 0) red[tid >> 6] = s;
    __syncthreads();
    const float mean = (red[0] + red[1] + red[2] + red[3]) * (1.0f / 1024.0f);
    const float dx = v.x - mean, dy = v.y - mean, dz = v.z - mean, dw = v.w - mean;
    float q = dx * dx + dy * dy + dz * dz + dw * dw;
    #pragma unroll
    for (int off = 32; off > 0; off >>= 1) q += __shfl_xor(q, off);
    if ((tid & 63) == 0) red[4 + (tid >> 6)] = q;
    __syncthreads();
    const float var = (red[4] + red[5] + red[6] + red[7]) * (1.0f / 1024.0f);
    const float rstd = rsqrtf(var + 1e-5f);
    const float4 scv = ((const float4*)sc)[tid];
    const float4 bsv = ((const float4*)bs)[tid];
    const u16 o0 = f2bf(dx * rstd * scv.x + bsv.x);
    const u16 o1 = f2bf(dy * rstd * scv.y + bsv.y);
    const u16 o2 = f2bf(dz * rstd * scv.z + bsv.z);
    const u16 o3 = f2bf(dw * rstd * scv.w + bsv.w);
    uint2 pk;
    pk.x = (uint32_t)o0 | ((uint32_t)o1 << 16);
    pk.y = (uint32_t)o2 | ((uint32_t)o3 << 16);
    *(uint2*)&zn[row * 1024 + tid * 4] = pk;
}

// ------------- cast+transpose: in fp32 [K,N] -> out bf16 [N,K] -------------
__global__ __launch_bounds__(256) void transpose_cast(const float* __restrict__ in,
                                                      u16* __restrict__ out,
                                                      int K, int N, int permute) {
    __shared__ float t[32][33];
    const int tid = threadIdx.x;
    const int j = tid & 31, i0 = tid >> 5;
    const int kb = blockIdx.y * 32, nb = blockIdx.x * 32;
    #pragma unroll
    for (int p = 0; p < 4; ++p) {
        int r = i0 + p * 8;
        t[r][j] = in[(size_t)(kb + r) * N + nb + j];
    }
    __syncthreads();
    #pragma unroll
    for (int p = 0; p < 4; ++p) {
        int r = i0 + p * 8;
        int c = nb + r;
        int np = c;
        if (permute) {
            int h = c / 192, rem = c - h * 192;
            int d = rem / 3, s = rem - d * 3;
            np = s * 1024 + h * 64 + d;
        }
        out[(size_t)np * K + kb + j] = f2bf(t[j][r]);
    }
}

// ---------------- GEMM1: zn[4096,1024] x wqkvT[3072,1024] ------------------
__global__ __launch_bounds__(256) void gemm_qkv(const u16* __restrict__ A,
                                                const u16* __restrict__ Bt,
                                                u16* __restrict__ qbuf,
                                                u16* __restrict__ kbuf,
                                                u16* __restrict__ vbuf) {
    __shared__ __align__(16) u16 As[128 * 32];
    __shared__ __align__(16) u16 Bs[128 * 32];
    const int tid = threadIdx.x;
    const int wave = tid >> 6, lane = tid & 63;
    const int quad = lane >> 4, l16 = lane & 15;
    const int wm = (wave >> 1) * 64, wn = (wave & 1) * 64;
    const int row0 = blockIdx.x * 128, col0 = blockIdx.y * 128;
    const int gr = lane >> 2, gc = (lane & 3) * 8;
    f32x4 acc[4][4] = {};
    for (int kt = 0; kt < 1024; kt += 32) {
        __syncthreads();
        #pragma unroll
        for (int i = 0; i < 2; ++i) {
            const int rb = wave * 16 + i * 64;
            gload_lds16(&A[(size_t)(row0 + rb + gr) * 1024 + kt + gc], &As[rb * 32]);
            gload_lds16(&Bt[(size_t)(col0 + rb + gr) * 1024 + kt + gc], &Bs[rb * 32]);
        }
        __syncthreads();
        bf16x8 ax[4], bx[4];
        #pragma unroll
        for (int t = 0; t < 4; ++t) {
            ax[t] = *(const bf16x8*)&As[(wm + t * 16 + l16) * 32 + quad * 8];
            bx[t] = *(const bf16x8*)&Bs[(wn + t * 16 + l16) * 32 + quad * 8];
        }
        #pragma unroll
        for (int mt = 0; mt < 4; ++mt)
            #pragma unroll
            for (int nt = 0; nt < 4; ++nt)
                acc[mt][nt] = __builtin_amdgcn_mfma_f32_16x16x32_bf16(ax[mt], bx[nt], acc[mt][nt], 0, 0, 0);
    }
    const int s = col0 >> 10;                 // block-uniform
    u16* const dst = (s == 0) ? qbuf : ((s == 1) ? kbuf : vbuf);
    const float scl = (s == 0) ? 0.125f * 1.44269504088896f : 1.0f;
    #pragma unroll
    for (int mt = 0; mt < 4; ++mt) {
        #pragma unroll
        for (int nt = 0; nt < 4; ++nt) {
            #pragma unroll
            for (int e = 0; e < 4; ++e) {
                const int row = row0 + wm + mt * 16 + quad * 4 + e;
                const int col = col0 + wn + nt * 16 + l16;
                const int b = row >> 11, n = row & 2047;
                const int h = (col >> 6) & 15, d = col & 63;
                dst[((size_t)(b * 16 + h) * 2048 + n) * 64 + d] = f2bf(acc[mt][nt][e] * scl);
            }
        }
    }
}

// ------------- V transpose: vbuf [bh,n,d] -> vT [bh,d,n] (bf16) -------------
__global__ __launch_bounds__(256) void transpose_v(const u16* __restrict__ vbuf,
                                                   u16* __restrict__ vT) {
    __shared__ u16 t[64][72];
    const int tid = threadIdx.x;
    const int bh = blockIdx.y, nb = blockIdx.x * 64;
    const int r = tid >> 3, c = (tid & 7) * 8;
    #pragma unroll
    for (int i = 0; i < 2; ++i)
        *(uint4*)&t[r + i * 32][c] = *(const uint4*)&vbuf[((size_t)bh * 2048 + nb + r + i * 32) * 64 + c];
    __syncthreads();
    #pragma unroll
    for (int i = 0; i < 2; ++i) {
        const int d = r + i * 32;
        u16 tmp[8];
        #pragma unroll
        for (int j = 0; j < 8; ++j) tmp[j] = t[c + j][d];
        *(uint4*)&vT[((size_t)bh * 64 + d) * 2048 + nb + c] = *(uint4*)tmp;
    }
}

// ---------------- Fused flash attention (key-split, dbuf DMA) ---------------
// grid (32 qt, 32 bh), block 128 (2 waves). Each block: 64 q rows.
// Wave w owns key-half [64w, 64w+64) of each 128-key tile, all 64 q (4 groups
// of 16). K/V double-buffered in LDS via global_load_lds, ONE barrier per tile
// (loads for kt+1 fly during compute of kt). Maxless softmax (q pre-scaled by
// 0.125*log2e, P=exp2(S)); l via MFMA against ones. Partial O/l summed across
// the two waves through LDS once at the end.
__global__ __launch_bounds__(128, 1) void attn_kernel(const u16* __restrict__ qb,
                                                      const u16* __restrict__ kb,
                                                      const u16* __restrict__ vT,
                                                      u16* __restrict__ att_out) {
    __shared__ __align__(16) u16 smem[32768];   // 64 KB: Ks[2]@0/8192, Vs[2]@16384/24576 (u16 units)
    const int tid = threadIdx.x;
    const int w = tid >> 6, lane = tid & 63;
    const int quad = lane >> 4, l16 = lane & 15;
    const int qt = blockIdx.x, bh = blockIdx.y;
    const int b = bh >> 4, h = bh & 15;

    // Q fragments (B operand): group g covers q = qt*64 + g*16 + l16
    bf16x8 qf[4][2];
    #pragma unroll
    for (int g = 0; g < 4; ++g) {
        const u16* qr = qb + ((size_t)bh * 2048 + qt * 64 + g * 16 + l16) * 64;
        qf[g][0] = *(const bf16x8*)&qr[quad * 8];
        qf[g][1] = *(const bf16x8*)&qr[32 + quad * 8];
    }

    // --- staging invariants (all per-lane, loop-invariant) ---
    // K: call j writes LDS rows p = j*16 + 8w + (lane>>3); row p holds key
    // kr(p) = {p6,p5,p3,p2,p4,p1,p0}; chunk swizzle slot = lane&7 holds data
    // chunk (lane&7)^(p&7).
    const int p0 = 8 * w + (lane >> 3);
    const int gk = (lane & 7) ^ ((lane >> 3) & 7);
    const int lanepart_k = ((p0 & 12) << 1) + (p0 & 3);
    const size_t kbh = (size_t)bh * 2048 * 64;
    // V: call j writes LDS rows d = j*8 + 4w + (lane>>4); slot lane&15 holds
    // data chunk (lane&15)^(d&15).
    const int dl = 4 * w + (lane >> 4);
    const int gv0 = (lane & 15) ^ dl;            // j even: d&15 = dl
    const int gv1 = (lane & 15) ^ (8 + dl);      // j odd:  d&15 = 8+dl
    const size_t vbh = (size_t)bh * 64 * 2048;
    const int jk[8] = {0, 4, 32, 36, 64, 68, 96, 100};  // kr contribution of j*16

    f32x4 o[4][4] = {};     // [group][vt] ; PV C-layout: q=quad*4+e, d=vt*16+l16
    f32x4 lacc[4] = {};     // [group]     ; l[q=quad*4+e], replicated over l16
    bf16x8 ones;
    #pragma unroll
    for (int i = 0; i < 8; ++i) ones[i] = (__bf16)1.0f;

    // prologue: stage tile 0 into buffer 0
    {
        u16* KsB = smem;
        u16* VsB = smem + 16384;
        #pragma unroll
        for (int j = 0; j < 8; ++j)
            gload_lds16(kb + kbh + (size_t)((jk[j] + lanepart_k) * 64 + gk * 8),
                        KsB + (j * 16 + 8 * w) * 64);
        #pragma unroll
        for (int j = 0; j < 8; ++j)
            gload_lds16(vT + vbh + (size_t)((j * 8 + dl) * 2048 + ((j & 1) ? gv1 : gv0) * 8),
                        VsB + (j * 8 + 4 * w) * 128);
    }

    for (int kt = 0; kt < 16; ++kt) {
        __syncthreads();   // drains this tile's DMA (vmcnt) + barrier
        if (kt < 15) {     // stage next tile into the other buffer; flies during compute
            const int nb_ = (kt + 1) & 1;
            u16* KsB = smem + nb_ * 8192;
            u16* VsB = smem + 16384 + nb_ * 8192;
            const int ko = (kt + 1) * 128;
            #pragma unroll
            for (int j = 0; j < 8; ++j)
                gload_lds16(kb + kbh + (size_t)((ko + jk[j] + lanepart_k) * 64 + gk * 8),
                            KsB + (j * 16 + 8 * w) * 64);
            #pragma unroll
            for (int j = 0; j < 8; ++j)
                gload_lds16(vT + vbh + (size_t)((j * 8 + dl) * 2048 + ko + ((j & 1) ? gv1 : gv0) * 8),
                            VsB + (j * 8 + 4 * w) * 128);
        }
        const u16* KsB = smem + (kt & 1) * 8192;
        const u16* VsB = smem + 16384 + (kt & 1) * 8192;

        // K fragments for this wave's 4 strips (held across all q-groups)
        bf16x8 kf[4][2];
        #pragma unroll
        for (int nt = 0; nt < 4; ++nt) {
            const int r = (4 * w + nt) * 16 + l16;
            kf[nt][0] = *(const bf16x8*)&KsB[r * 64 + ((quad ^ (r & 7)) << 3)];
            kf[nt][1] = *(const bf16x8*)&KsB[r * 64 + (((quad + 4) ^ (r & 7)) << 3)];
        }

        // S^T = K·Q^T per group, exp2 straight into PV A-fragments (in-lane)
        bf16x8 ap[4][2];
        #pragma unroll
        for (int g = 0; g < 4; ++g) {
            f32x4 s[4] = {};
            #pragma unroll
            for (int nt = 0; nt < 4; ++nt) {
                s[nt] = __builtin_amdgcn_mfma_f32_16x16x32_bf16(kf[nt][0], qf[g][0], s[nt], 0, 0, 0);
                s[nt] = __builtin_amdgcn_mfma_f32_16x16x32_bf16(kf[nt][1], qf[g][1], s[nt], 0, 0, 0);
            }
            #pragma unroll
            for (int nt = 0; nt < 4; ++nt)
                #pragma unroll
                for (int e = 0; e < 4; ++e)
                    ap[g][nt >> 1][(nt & 1) * 4 + e] = (__bf16)exp2f(s[nt][e]);
        }

        // O += P·V over this wave's key-half; V fragments shared across groups
        #pragma unroll
        for (int vt = 0; vt < 4; ++vt) {
            const int d = vt * 16 + l16;
            #pragma unroll
            for (int cl = 0; cl < 2; ++cl) {
                const bf16x8 vf = *(const bf16x8*)&VsB[d * 128 + ((((2 * w + cl) * 4 + quad) ^ l16) << 3)];
                #pragma unroll
                for (int g = 0; g < 4; ++g)
                    o[g][vt] = __builtin_amdgcn_mfma_f32_16x16x32_bf16(ap[g][cl], vf, o[g][vt], 0, 0, 0);
            }
        }
        #pragma unroll
        for (int cl = 0; cl < 2; ++cl)
            #pragma unroll
            for (int g = 0; g < 4; ++g)
                lacc[g] = __builtin_amdgcn_mfma_f32_16x16x32_bf16(ap[g][cl], ones, lacc[g], 0, 0, 0);
    }

    // ---- cross-wave reduction: wave w gives away groups {2-2w, 3-2w}, keeps the rest
    __syncthreads();
    float* Ox = (float*)smem;              // [4 groups][16 q][68 d]
    float* lx = Ox + 4 * 16 * 68;          // [4 groups][16 q]
    const int give0 = (w == 0) ? 2 : 0;
    #pragma unroll
    for (int gi = 0; gi < 2; ++gi) {
        const int g = give0 + gi;
        #pragma unroll
        for (int vt = 0; vt < 4; ++vt)
            #pragma unroll
            for (int e = 0; e < 4; ++e)
                Ox[(g * 16 + quad * 4 + e) * 68 + vt * 16 + l16] = o[g][vt][e];
        if (l16 == 0) {
            #pragma unroll
            for (int e = 0; e < 4; ++e) lx[g * 16 + quad * 4 + e] = lacc[g][e];
        }
    }
    __syncthreads();
    const int keep0 = (w == 0) ? 0 : 2;
    #pragma unroll
    for (int gi = 0; gi < 2; ++gi) {
        const int g = keep0 + gi;
        #pragma unroll
        for (int e = 0; e < 4; ++e) {
            const float lt = lacc[g][e] + lx[g * 16 + quad * 4 + e];
            const float inv = 1.0f / lt;
            const int n = qt * 64 + g * 16 + quad * 4 + e;
            #pragma unroll
            for (int vt = 0; vt < 4; ++vt) {
                const float ov = o[g][vt][e] + Ox[(g * 16 + quad * 4 + e) * 68 + vt * 16 + l16];
                att_out[(size_t)(b * 2048 + n) * 1024 + h * 64 + vt * 16 + l16] = f2bf(ov * inv);
            }
        }
    }
}

// ---- GEMM2: att_out[4096,1024] x wprojT[1024,1024] + bias + z -> out fp32 ----
__global__ __launch_bounds__(256) void gemm_proj(const u16* __restrict__ A,
                                                 const u16* __restrict__ Bt,
                                                 const float* __restrict__ bias,
                                                 const float* __restrict__ z,
                                                 float* __restrict__ out) {
    __shared__ __align__(16) u16 As[64 * 32];
    __shared__ __align__(16) u16 Bs[128 * 32];
    const int tid = threadIdx.x;
    const int wave = tid >> 6, lane = tid & 63;
    const int quad = lane >> 4, l16 = lane & 15;
    const int wm = (wave >> 1) * 32, wn = (wave & 1) * 64;
    const int row0 = blockIdx.x * 64, col0 = blockIdx.y * 128;
    const int gr = lane >> 2, gc = (lane & 3) * 8;
    f32x4 acc[2][4] = {};
    for (int kt = 0; kt < 1024; kt += 32) {
        __syncthreads();
        gload_lds16(&A[(size_t)(row0 + wave * 16 + gr) * 1024 + kt + gc], &As[(wave * 16) * 32]);
        #pragma unroll
        for (int i = 0; i < 2; ++i) {
            const int rb = wave * 16 + i * 64;
            gload_lds16(&Bt[(size_t)(col0 + rb + gr) * 1024 + kt + gc], &Bs[rb * 32]);
        }
        __syncthreads();
        bf16x8 ax[2], bx[4];
        #pragma unroll
        for (int t = 0; t < 2; ++t)
            ax[t] = *(const bf16x8*)&As[(wm + t * 16 + l16) * 32 + quad * 8];
        #pragma unroll
        for (int t = 0; t < 4; ++t)
            bx[t] = *(const bf16x8*)&Bs[(wn + t * 16 + l16) * 32 + quad * 8];
        #pragma unroll
        for (int mt = 0; mt < 2; ++mt)
            #pragma unroll
            for (int nt = 0; nt < 4; ++nt)
                acc[mt][nt] = __builtin_amdgcn_mfma_f32_16x16x32_bf16(ax[mt], bx[nt], acc[mt][nt], 0, 0, 0);
    }
    #pragma unroll
    for (int mt = 0; mt < 2; ++mt) {
        #pragma unroll
        for (int nt = 0; nt < 4; ++nt) {
            #pragma unroll
            for (int e = 0; e < 4; ++e) {
                const int row = row0 + wm + mt * 16 + quad * 4 + e;
                const int col = col0 + wn + nt * 16 + l16;
                out[(size_t)row * 1024 + col] = acc[mt][nt][e] + bias[col] + z[(size_t)row * 1024 + col];
            }
        }
    }
}

extern "C" void kernel_launch(void* const* d_in, const int* in_sizes, int n_in,
                              void* d_out, int out_size, void* d_ws, size_t ws_size,
                              hipStream_t stream) {
    const float* z        = (const float*)d_in[0];
    const float* ln_scale = (const float*)d_in[1];
    const float* ln_bias  = (const float*)d_in[2];
    const float* w_qkv    = (const float*)d_in[3];
    const float* w_proj   = (const float*)d_in[4];
    const float* b_proj   = (const float*)d_in[5];
    float* out = (float*)d_out;

    char* ws = (char*)d_ws;
    u16* zn     = (u16*)(ws);                       // 0-8 MiB   [4096,1024]
    u16* vT     = (u16*)(ws);                       // aliases zn (zn dead after gemm_qkv)
    u16* wqkvT  = (u16*)(ws + (8u << 20));          // 8-14 MiB  [3072,1024] (rows permuted)
    u16* wprojT = (u16*)(ws + (14u << 20));         // 14-16 MiB [1024,1024]
    u16* qbuf   = (u16*)(ws + (16u << 20));         // 16-24 MiB [32,2048,64] (pre-scaled 0.125*log2e)
    u16* kbuf   = (u16*)(ws + (24u << 20));         // 24-32 MiB [32,2048,64]
    u16* vbuf   = (u16*)(ws + (32u << 20));         // 32-40 MiB [32,2048,64]
    u16* att_o  = (u16*)(ws + (40u << 20));         // 40-48 MiB [4096,1024]

    ln_kernel<<<dim3(4096), 256, 0, stream>>>(z, ln_scale, ln_bias, zn);
    transpose_cast<<<dim3(96, 32), 256, 0, stream>>>(w_qkv, wqkvT, 1024, 3072, 1);
    transpose_cast<<<dim3(32, 32), 256, 0, stream>>>(w_proj, wprojT, 1024, 1024, 0);
    gemm_qkv<<<dim3(32, 24), 256, 0, stream>>>(zn, wqkvT, qbuf, kbuf, vbuf);
    transpose_v<<<dim3(32, 32), 256, 0, stream>>>(vbuf, vT);
    attn_kernel<<<dim3(32, 32), 128, 0, stream>>>(qbuf, kbuf, vT, att_o);
    gemm_proj<<<dim3(64, 8), 256, 0, stream>>>(att_o, wprojT, b_proj, z, out);
}

// Round 6
// 203.160 us; speedup vs baseline: 1.5963x; 1.5963x over previous
//
#include <hip/hip_runtime.h>
#include <stdint.h>
#include <math.h>

typedef unsigned short u16;
typedef float f32x4 __attribute__((ext_vector_type(4)));
typedef __bf16 bf16x8 __attribute__((ext_vector_type(8)));

__device__ __forceinline__ u16 f2bf(float f) {
    union { float f; uint32_t u; } c; c.f = f;
    return (u16)((c.u + 0x7FFFu + ((c.u >> 16) & 1u)) >> 16);
}

__device__ __forceinline__ void gload_lds16(const void* g, void* l) {
    __builtin_amdgcn_global_load_lds(
        (const __attribute__((address_space(1))) unsigned int*)g,
        (__attribute__((address_space(3))) unsigned int*)l, 16, 0, 0);
}

// ---------------- LayerNorm: z [4096,1024] fp32 -> zn bf16 ----------------
__global__ __launch_bounds__(256) void ln_kernel(const float* __restrict__ z,
                                                 const float* __restrict__ sc,
                                                 const float* __restrict__ bs,
                                                 u16* __restrict__ zn) {
    const int row = blockIdx.x, tid = threadIdx.x;
    const float4 v = ((const float4*)(z + row * 1024))[tid];
    float s = v.x + v.y + v.z + v.w;
    #pragma unroll
    for (int off = 32; off > 0; off >>= 1) s += __shfl_xor(s, off);
    __shared__ float red[8];
    if ((tid & 63) == 0) red[tid >> 6] = s;
    __syncthreads();
    const float mean = (red[0] + red[1] + red[2] + red[3]) * (1.0f / 1024.0f);
    const float dx = v.x - mean, dy = v.y - mean, dz = v.z - mean, dw = v.w - mean;
    float q = dx * dx + dy * dy + dz * dz + dw * dw;
    #pragma unroll
    for (int off = 32; off > 0; off >>= 1) q += __shfl_xor(q, off);
    if ((tid & 63) == 0) red[4 + (tid >> 6)] = q;
    __syncthreads();
    const float var = (red[4] + red[5] + red[6] + red[7]) * (1.0f / 1024.0f);
    const float rstd = rsqrtf(var + 1e-5f);
    const float4 scv = ((const float4*)sc)[tid];
    const float4 bsv = ((const float4*)bs)[tid];
    const u16 o0 = f2bf(dx * rstd * scv.x + bsv.x);
    const u16 o1 = f2bf(dy * rstd * scv.y + bsv.y);
    const u16 o2 = f2bf(dz * rstd * scv.z + bsv.z);
    const u16 o3 = f2bf(dw * rstd * scv.w + bsv.w);
    uint2 pk;
    pk.x = (uint32_t)o0 | ((uint32_t)o1 << 16);
    pk.y = (uint32_t)o2 | ((uint32_t)o3 << 16);
    *(uint2*)&zn[row * 1024 + tid * 4] = pk;
}

// ------------- cast+transpose: in fp32 [K,N] -> out bf16 [N,K] -------------
__global__ __launch_bounds__(256) void transpose_cast(const float* __restrict__ in,
                                                      u16* __restrict__ out,
                                                      int K, int N, int permute) {
    __shared__ float t[32][33];
    const int tid = threadIdx.x;
    const int j = tid & 31, i0 = tid >> 5;
    const int kb = blockIdx.y * 32, nb = blockIdx.x * 32;
    #pragma unroll
    for (int p = 0; p < 4; ++p) {
        int r = i0 + p * 8;
        t[r][j] = in[(size_t)(kb + r) * N + nb + j];
    }
    __syncthreads();
    #pragma unroll
    for (int p = 0; p < 4; ++p) {
        int r = i0 + p * 8;
        int c = nb + r;
        int np = c;
        if (permute) {
            int h = c / 192, rem = c - h * 192;
            int d = rem / 3, s = rem - d * 3;
            np = s * 1024 + h * 64 + d;
        }
        out[(size_t)np * K + kb + j] = f2bf(t[j][r]);
    }
}

// ---------------- GEMM1: zn[4096,1024] x wqkvT[3072,1024] ------------------
__global__ __launch_bounds__(256) void gemm_qkv(const u16* __restrict__ A,
                                                const u16* __restrict__ Bt,
                                                u16* __restrict__ qbuf,
                                                u16* __restrict__ kbuf,
                                                u16* __restrict__ vbuf) {
    __shared__ __align__(16) u16 As[128 * 32];
    __shared__ __align__(16) u16 Bs[128 * 32];
    const int tid = threadIdx.x;
    const int wave = tid >> 6, lane = tid & 63;
    const int quad = lane >> 4, l16 = lane & 15;
    const int wm = (wave >> 1) * 64, wn = (wave & 1) * 64;
    const int row0 = blockIdx.x * 128, col0 = blockIdx.y * 128;
    const int gr = lane >> 2, gc = (lane & 3) * 8;
    f32x4 acc[4][4] = {};
    for (int kt = 0; kt < 1024; kt += 32) {
        __syncthreads();
        #pragma unroll
        for (int i = 0; i < 2; ++i) {
            const int rb = wave * 16 + i * 64;
            gload_lds16(&A[(size_t)(row0 + rb + gr) * 1024 + kt + gc], &As[rb * 32]);
            gload_lds16(&Bt[(size_t)(col0 + rb + gr) * 1024 + kt + gc], &Bs[rb * 32]);
        }
        __syncthreads();
        bf16x8 ax[4], bx[4];
        #pragma unroll
        for (int t = 0; t < 4; ++t) {
            ax[t] = *(const bf16x8*)&As[(wm + t * 16 + l16) * 32 + quad * 8];
            bx[t] = *(const bf16x8*)&Bs[(wn + t * 16 + l16) * 32 + quad * 8];
        }
        #pragma unroll
        for (int mt = 0; mt < 4; ++mt)
            #pragma unroll
            for (int nt = 0; nt < 4; ++nt)
                acc[mt][nt] = __builtin_amdgcn_mfma_f32_16x16x32_bf16(ax[mt], bx[nt], acc[mt][nt], 0, 0, 0);
    }
    const int s = col0 >> 10;                 // block-uniform
    u16* const dst = (s == 0) ? qbuf : ((s == 1) ? kbuf : vbuf);
    const float scl = (s == 0) ? 0.125f * 1.44269504088896f : 1.0f;
    #pragma unroll
    for (int mt = 0; mt < 4; ++mt) {
        #pragma unroll
        for (int nt = 0; nt < 4; ++nt) {
            #pragma unroll
            for (int e = 0; e < 4; ++e) {
                const int row = row0 + wm + mt * 16 + quad * 4 + e;
                const int col = col0 + wn + nt * 16 + l16;
                const int b = row >> 11, n = row & 2047;
                const int h = (col >> 6) & 15, d = col & 63;
                dst[((size_t)(b * 16 + h) * 2048 + n) * 64 + d] = f2bf(acc[mt][nt][e] * scl);
            }
        }
    }
}

// ------------- V transpose: vbuf [bh,n,d] -> vT [bh,d,n] (bf16) -------------
__global__ __launch_bounds__(256) void transpose_v(const u16* __restrict__ vbuf,
                                                   u16* __restrict__ vT) {
    __shared__ u16 t[64][72];
    const int tid = threadIdx.x;
    const int bh = blockIdx.y, nb = blockIdx.x * 64;
    const int r = tid >> 3, c = (tid & 7) * 8;
    #pragma unroll
    for (int i = 0; i < 2; ++i)
        *(uint4*)&t[r + i * 32][c] = *(const uint4*)&vbuf[((size_t)bh * 2048 + nb + r + i * 32) * 64 + c];
    __syncthreads();
    #pragma unroll
    for (int i = 0; i < 2; ++i) {
        const int d = r + i * 32;
        u16 tmp[8];
        #pragma unroll
        for (int j = 0; j < 8; ++j) tmp[j] = t[c + j][d];
        *(uint4*)&vT[((size_t)bh * 64 + d) * 2048 + nb + c] = *(uint4*)tmp;
    }
}

// ---------------- Fused flash attention (R4 structure + dbuf DMA) ----------
// 128-q blocks (4 waves, 32 q each), 128-key tiles, LDS double-buffered
// (64 KB total), ONE barrier per tile: stage(kt+1) flies during compute(kt).
// Maxless softmax (q pre-scaled 0.125*log2e, P=exp2(S)); denominator via MFMA
// against ones. K rows permuted in LDS so exp'd S^T C-layout values are the
// PV A-fragment in-lane; XOR chunk swizzle keeps all LDS conflict-free.
__global__ __launch_bounds__(256) void attn_kernel(const u16* __restrict__ qb,
                                                   const u16* __restrict__ kb,
                                                   const u16* __restrict__ vT,
                                                   u16* __restrict__ att_out) {
    // [buf][ Ks 128*64 | Vs 64*128 ] : 2 * 16384 u16 = 64 KB
    __shared__ __align__(16) u16 smem[2][16384];
    const int tid = threadIdx.x;
    const int wave = tid >> 6, lane = tid & 63;
    const int quad = lane >> 4, l16 = lane & 15;
    const int qt = blockIdx.x, bh = blockIdx.y;
    const int b = bh >> 4, h = bh & 15;

    // Q fragments in registers (B operand), two 16-row groups per wave
    const u16* qrowA = &qb[(size_t)(bh * 2048 + qt * 128 + wave * 32 + l16) * 64];
    const bf16x8 qA0 = *(const bf16x8*)&qrowA[quad * 8];
    const bf16x8 qA1 = *(const bf16x8*)&qrowA[32 + quad * 8];
    const u16* qrowB = qrowA + 16 * 64;
    const bf16x8 qB0 = *(const bf16x8*)&qrowB[quad * 8];
    const bf16x8 qB1 = *(const bf16x8*)&qrowB[32 + quad * 8];

    // staging source pointers (per-lane, advanced each tile)
    const u16* ksrc[4];
    const u16* vsrc[4];
    int kofs[4], vofs[4];
    #pragma unroll
    for (int j = 0; j < 4; ++j) {
        const int p = 8 * wave + 32 * j + (lane >> 3);         // LDS K-row
        const int kr = (p & 0x60) | ((p & 12) << 1) | ((p & 16) >> 2) | (p & 3);
        const int gk = (lane & 7) ^ (p & 7);                   // swizzled chunk
        ksrc[j] = kb + ((size_t)bh * 2048 + kr) * 64 + gk * 8;
        kofs[j] = (8 * wave + 32 * j) * 64;
        const int d = 4 * wave + 16 * j + (lane >> 4);         // LDS V-row
        const int gv = (lane & 15) ^ (d & 15);
        vsrc[j] = vT + ((size_t)bh * 64 + d) * 2048 + gv * 8;
        vofs[j] = 8192 + (4 * wave + 16 * j) * 128;
    }

    f32x4 oA[4] = {}, oB[4] = {};
    f32x4 lA = {}, lB = {};
    bf16x8 ones;
    #pragma unroll
    for (int i = 0; i < 8; ++i) ones[i] = (__bf16)1.0f;

    // prologue: stage tile 0 into buffer 0
    #pragma unroll
    for (int j = 0; j < 4; ++j) {
        gload_lds16(ksrc[j], &smem[0][kofs[j]]);
        gload_lds16(vsrc[j], &smem[0][vofs[j]]);
        ksrc[j] += 128 * 64;
        vsrc[j] += 128;
    }

    for (int kt = 0; kt < 16; ++kt) {
        __syncthreads();   // drains tile-kt DMA; prefetch below flies over compute
        if (kt < 15) {
            u16* nb_ = smem[(kt + 1) & 1];
            #pragma unroll
            for (int j = 0; j < 4; ++j) {
                gload_lds16(ksrc[j], &nb_[kofs[j]]);
                gload_lds16(vsrc[j], &nb_[vofs[j]]);
                ksrc[j] += 128 * 64;
                vsrc[j] += 128;
            }
        }
        const u16* Ks = smem[kt & 1];
        const u16* Vs = smem[kt & 1] + 8192;

        // S^T = K·Q^T for both q-groups; K fragments shared
        f32x4 sA[8] = {}, sB[8] = {};
        #pragma unroll
        for (int nt = 0; nt < 8; ++nt) {
            const int r = nt * 16 + l16;
            const bf16x8 k0 = *(const bf16x8*)&Ks[r * 64 + (((quad) ^ (r & 7)) << 3)];
            const bf16x8 k1 = *(const bf16x8*)&Ks[r * 64 + (((quad + 4) ^ (r & 7)) << 3)];
            sA[nt] = __builtin_amdgcn_mfma_f32_16x16x32_bf16(k0, qA0, sA[nt], 0, 0, 0);
            sA[nt] = __builtin_amdgcn_mfma_f32_16x16x32_bf16(k1, qA1, sA[nt], 0, 0, 0);
            sB[nt] = __builtin_amdgcn_mfma_f32_16x16x32_bf16(k0, qB0, sB[nt], 0, 0, 0);
            sB[nt] = __builtin_amdgcn_mfma_f32_16x16x32_bf16(k1, qB1, sB[nt], 0, 0, 0);
        }

        // P = exp2(S) straight into PV A-fragments (in-lane)
        bf16x8 apA[4], apB[4];
        #pragma unroll
        for (int nt = 0; nt < 8; ++nt) {
            #pragma unroll
            for (int e = 0; e < 4; ++e) {
                apA[nt >> 1][(nt & 1) * 4 + e] = (__bf16)exp2f(sA[nt][e]);
                apB[nt >> 1][(nt & 1) * 4 + e] = (__bf16)exp2f(sB[nt][e]);
            }
        }

        // O += P·V (V fragments shared between groups); l += P·1
        #pragma unroll
        for (int vt = 0; vt < 4; ++vt) {
            const int dd = vt * 16 + l16;
            #pragma unroll
            for (int c = 0; c < 4; ++c) {
                const bf16x8 vf = *(const bf16x8*)&Vs[dd * 128 + (((c * 4 + quad) ^ l16) << 3)];
                oA[vt] = __builtin_amdgcn_mfma_f32_16x16x32_bf16(apA[c], vf, oA[vt], 0, 0, 0);
                oB[vt] = __builtin_amdgcn_mfma_f32_16x16x32_bf16(apB[c], vf, oB[vt], 0, 0, 0);
            }
        }
        #pragma unroll
        for (int c = 0; c < 4; ++c) {
            lA = __builtin_amdgcn_mfma_f32_16x16x32_bf16(apA[c], ones, lA, 0, 0, 0);
            lB = __builtin_amdgcn_mfma_f32_16x16x32_bf16(apB[c], ones, lB, 0, 0, 0);
        }
    }

    #pragma unroll
    for (int e = 0; e < 4; ++e) {
        const float invA = 1.0f / lA[e];
        const float invB = 1.0f / lB[e];
        const int nA = qt * 128 + wave * 32 + quad * 4 + e;
        #pragma unroll
        for (int vt = 0; vt < 4; ++vt) {
            att_out[(size_t)(b * 2048 + nA) * 1024 + h * 64 + vt * 16 + l16] = f2bf(oA[vt][e] * invA);
            att_out[(size_t)(b * 2048 + nA + 16) * 1024 + h * 64 + vt * 16 + l16] = f2bf(oB[vt][e] * invB);
        }
    }
}

// ---- GEMM2: att_out[4096,1024] x wprojT[1024,1024] + bias + z -> out fp32 ----
__global__ __launch_bounds__(256) void gemm_proj(const u16* __restrict__ A,
                                                 const u16* __restrict__ Bt,
                                                 const float* __restrict__ bias,
                                                 const float* __restrict__ z,
                                                 float* __restrict__ out) {
    __shared__ __align__(16) u16 As[64 * 32];
    __shared__ __align__(16) u16 Bs[128 * 32];
    const int tid = threadIdx.x;
    const int wave = tid >> 6, lane = tid & 63;
    const int quad = lane >> 4, l16 = lane & 15;
    const int wm = (wave >> 1) * 32, wn = (wave & 1) * 64;
    const int row0 = blockIdx.x * 64, col0 = blockIdx.y * 128;
    const int gr = lane >> 2, gc = (lane & 3) * 8;
    f32x4 acc[2][4] = {};
    for (int kt = 0; kt < 1024; kt += 32) {
        __syncthreads();
        gload_lds16(&A[(size_t)(row0 + wave * 16 + gr) * 1024 + kt + gc], &As[(wave * 16) * 32]);
        #pragma unroll
        for (int i = 0; i < 2; ++i) {
            const int rb = wave * 16 + i * 64;
            gload_lds16(&Bt[(size_t)(col0 + rb + gr) * 1024 + kt + gc], &Bs[rb * 32]);
        }
        __syncthreads();
        bf16x8 ax[2], bx[4];
        #pragma unroll
        for (int t = 0; t < 2; ++t)
            ax[t] = *(const bf16x8*)&As[(wm + t * 16 + l16) * 32 + quad * 8];
        #pragma unroll
        for (int t = 0; t < 4; ++t)
            bx[t] = *(const bf16x8*)&Bs[(wn + t * 16 + l16) * 32 + quad * 8];
        #pragma unroll
        for (int mt = 0; mt < 2; ++mt)
            #pragma unroll
            for (int nt = 0; nt < 4; ++nt)
                acc[mt][nt] = __builtin_amdgcn_mfma_f32_16x16x32_bf16(ax[mt], bx[nt], acc[mt][nt], 0, 0, 0);
    }
    #pragma unroll
    for (int mt = 0; mt < 2; ++mt) {
        #pragma unroll
        for (int nt = 0; nt < 4; ++nt) {
            #pragma unroll
            for (int e = 0; e < 4; ++e) {
                const int row = row0 + wm + mt * 16 + quad * 4 + e;
                const int col = col0 + wn + nt * 16 + l16;
                out[(size_t)row * 1024 + col] = acc[mt][nt][e] + bias[col] + z[(size_t)row * 1024 + col];
            }
        }
    }
}

extern "C" void kernel_launch(void* const* d_in, const int* in_sizes, int n_in,
                              void* d_out, int out_size, void* d_ws, size_t ws_size,
                              hipStream_t stream) {
    const float* z        = (const float*)d_in[0];
    const float* ln_scale = (const float*)d_in[1];
    const float* ln_bias  = (const float*)d_in[2];
    const float* w_qkv    = (const float*)d_in[3];
    const float* w_proj   = (const float*)d_in[4];
    const float* b_proj   = (const float*)d_in[5];
    float* out = (float*)d_out;

    char* ws = (char*)d_ws;
    u16* zn     = (u16*)(ws);                       // 0-8 MiB   [4096,1024]
    u16* vT     = (u16*)(ws);                       // aliases zn (zn dead after gemm_qkv)
    u16* wqkvT  = (u16*)(ws + (8u << 20));          // 8-14 MiB  [3072,1024] (rows permuted)
    u16* wprojT = (u16*)(ws + (14u << 20));         // 14-16 MiB [1024,1024]
    u16* qbuf   = (u16*)(ws + (16u << 20));         // 16-24 MiB [32,2048,64] (pre-scaled 0.125*log2e)
    u16* kbuf   = (u16*)(ws + (24u << 20));         // 24-32 MiB [32,2048,64]
    u16* vbuf   = (u16*)(ws + (32u << 20));         // 32-40 MiB [32,2048,64]
    u16* att_o  = (u16*)(ws + (40u << 20));         // 40-48 MiB [4096,1024]

    ln_kernel<<<dim3(4096), 256, 0, stream>>>(z, ln_scale, ln_bias, zn);
    transpose_cast<<<dim3(96, 32), 256, 0, stream>>>(w_qkv, wqkvT, 1024, 3072, 1);
    transpose_cast<<<dim3(32, 32), 256, 0, stream>>>(w_proj, wprojT, 1024, 1024, 0);
    gemm_qkv<<<dim3(32, 24), 256, 0, stream>>>(zn, wqkvT, qbuf, kbuf, vbuf);
    transpose_v<<<dim3(32, 32), 256, 0, stream>>>(vbuf, vT);
    attn_kernel<<<dim3(16, 32), 256, 0, stream>>>(qbuf, kbuf, vT, att_o);
    gemm_proj<<<dim3(64, 8), 256, 0, stream>>>(att_o, wprojT, b_proj, z, out);
}